// Round 6
// baseline (887.605 us; speedup 1.0000x reference)
//
#include <hip/hip_runtime.h>
#include <hip/hip_bf16.h>

#define DIM 768
#define NH 12
#define HD 64
#define SEQ 1024
#define BATCH 8
#define JSPA 2      // j-split for the denominator pass
#define JSPB 2      // j-split for the PV pass
#define LOG2E 1.44269504f

typedef __bf16 bf16x8 __attribute__((ext_vector_type(8)));
typedef _Float16 f16x4 __attribute__((ext_vector_type(4)));
typedef _Float16 f16x8 __attribute__((ext_vector_type(8)));
typedef float f32x4 __attribute__((ext_vector_type(4)));

// ---------------------------------------------------------------------------
// K-1: convert X fp32 -> bf16 (one-shot, ~38 MB traffic).
// ---------------------------------------------------------------------------
__global__ __launch_bounds__(256) void xcvt(
    const float* __restrict__ X, __bf16* __restrict__ Xb)
{
  const size_t i = ((size_t)blockIdx.x * 256 + threadIdx.x) * 8;
  float4 a0 = *(const float4*)(X + i);
  float4 a1 = *(const float4*)(X + i + 4);
  bf16x8 v = { (__bf16)a0.x, (__bf16)a0.y, (__bf16)a0.z, (__bf16)a0.w,
               (__bf16)a1.x, (__bf16)a1.y, (__bf16)a1.z, (__bf16)a1.w };
  *(bf16x8*)(Xb + i) = v;
}

// ---------------------------------------------------------------------------
// K0: transpose + cvt 768x768 fp32 W -> WT[n][k]. blockIdx.z selects.
// Wq/Wk/Wv -> bf16; Wp -> f16 (paired with f16 attention partials).
// ---------------------------------------------------------------------------
__global__ __launch_bounds__(256) void wtrans(
    const float* __restrict__ Wq, const float* __restrict__ Wk,
    const float* __restrict__ Wv, const float* __restrict__ Wp,
    __bf16* __restrict__ Tq, __bf16* __restrict__ Tk,
    __bf16* __restrict__ Tv, _Float16* __restrict__ Tp)
{
  const int z = blockIdx.z;
  const float* W = (z==0) ? Wq : (z==1) ? Wk : (z==2) ? Wv : Wp;
  __shared__ float tile[32][33];
  const int t = threadIdx.x, tx = t & 31, ty = t >> 5;
  const int k0 = blockIdx.y * 32, n0 = blockIdx.x * 32;
#pragma unroll
  for (int u = 0; u < 4; ++u)
    tile[ty + u*8][tx] = W[(size_t)(k0 + ty + u*8) * DIM + n0 + tx];
  __syncthreads();
  if (z == 3) {
#pragma unroll
    for (int u = 0; u < 4; ++u)
      Tp[(size_t)(n0 + ty + u*8) * DIM + k0 + tx] = (_Float16)tile[tx][ty + u*8];
  } else {
    __bf16* T = (z==0) ? Tq : (z==1) ? Tk : Tv;
#pragma unroll
    for (int u = 0; u < 4; ++u)
      T[(size_t)(n0 + ty + u*8) * DIM + k0 + tx] = (__bf16)tile[tx][ty + u*8];
  }
}

// ---------------------------------------------------------------------------
// K1: fused QKV projection, LDS-staged MFMA GEMM (unchanged, proven).
// ---------------------------------------------------------------------------
__global__ __launch_bounds__(256) void gemm_qkv(
    const __bf16* __restrict__ Xb, const __bf16* __restrict__ WT,
    __bf16* __restrict__ Qo, __bf16* __restrict__ Ko, _Float16* __restrict__ Vt2)
{
  __shared__ __bf16 As[128 * 40];
  __shared__ __bf16 Bs[128 * 40];

  const int t = threadIdx.x, lane = t & 63, w = t >> 6;
  const int n16 = lane & 15, q = lane >> 4;
  const int m0 = blockIdx.y * 128, n0 = blockIdx.x * 128;
  const int wm = (w >> 1) * 64, wn = (w & 1) * 64;

  const int srow = t >> 2, scol = (t & 3) * 8;
  const __bf16* Ag = Xb + (size_t)(m0 + srow) * DIM + scol;
  const __bf16* Bg = WT + (size_t)(n0 + srow) * DIM + scol;

  f32x4 acc[4][4];
#pragma unroll
  for (int mt = 0; mt < 4; ++mt)
#pragma unroll
    for (int nt = 0; nt < 4; ++nt) acc[mt][nt] = (f32x4){0.f,0.f,0.f,0.f};

  for (int kb = 0; kb < DIM; kb += 32) {
    __syncthreads();
    bf16x8 a0 = *(const bf16x8*)(Ag + kb);
    bf16x8 a1 = *(const bf16x8*)(Ag + (size_t)64 * DIM + kb);
    bf16x8 b0 = *(const bf16x8*)(Bg + kb);
    bf16x8 b1 = *(const bf16x8*)(Bg + (size_t)64 * DIM + kb);
    *(bf16x8*)&As[srow * 40 + scol] = a0;
    *(bf16x8*)&As[(srow + 64) * 40 + scol] = a1;
    *(bf16x8*)&Bs[srow * 40 + scol] = b0;
    *(bf16x8*)&Bs[(srow + 64) * 40 + scol] = b1;
    __syncthreads();

    bf16x8 af[4], bg[4];
#pragma unroll
    for (int mt = 0; mt < 4; ++mt)
      af[mt] = *(const bf16x8*)&As[(wm + mt*16 + n16) * 40 + q*8];
#pragma unroll
    for (int nt = 0; nt < 4; ++nt)
      bg[nt] = *(const bf16x8*)&Bs[(wn + nt*16 + n16) * 40 + q*8];
#pragma unroll
    for (int mt = 0; mt < 4; ++mt)
#pragma unroll
      for (int nt = 0; nt < 4; ++nt)
        acc[mt][nt] = __builtin_amdgcn_mfma_f32_16x16x32_bf16(af[mt], bg[nt], acc[mt][nt], 0, 0, 0);
  }

#pragma unroll
  for (int nt = 0; nt < 4; ++nt) {
    const int n = n0 + wn + nt*16 + n16;
    const int z = n / DIM, c = n % DIM;
    const int h = c >> 6, d = c & 63;
#pragma unroll
    for (int mt = 0; mt < 4; ++mt) {
#pragma unroll
      for (int r = 0; r < 4; ++r) {
        const int row = m0 + wm + mt*16 + q*4 + r;
        const int bb = row >> 10, ii = row & 1023;
        const float v = acc[mt][nt][r];
        if (z == 0)
          Qo[(((size_t)bb*NH + h)*SEQ + ii)*HD + d] = (__bf16)(v * 0.125f);
        else if (z == 1)
          Ko[(((size_t)bb*NH + h)*SEQ + ii)*HD + d] = (__bf16)v;
        else
          Vt2[((((size_t)bb*NH + h)*64 + (ii >> 4))*HD + d)*16 + (ii & 15)] = (_Float16)v;
      }
    }
  }
}

// ---------------------------------------------------------------------------
// K2a: softmax-denominator pass, j-split 2 ways, grid (8, 64, 2) = 1024
// = 4 blocks/CU exact. NO register rotation: kC loaded at interval start,
// used at interval end (K is L2-resident per round-4 FETCH measurement);
// lag-1 accumulate-mix fills the gap. (256,4) caps total regs at 128/wave
// -> 4 waves/SIMD resident (round-5 lesson: unified VGPR+AGPR file).
// ---------------------------------------------------------------------------
__global__ __launch_bounds__(256, 4) void attn_sums(
    const __bf16* __restrict__ Qg, const __bf16* __restrict__ Kg,
    const float* __restrict__ Wl, const float* __restrict__ bl,
    float* __restrict__ lpart)
{
  __shared__ _Float16 Sl[2][12][324];

  const int t = threadIdx.x, lane = t & 63, w = t >> 6;
  const int n16 = lane & 15, q = lane >> 4;
  const int h0 = w * 3;
  const int b = blockIdx.x, i0 = blockIdx.y * 16, z = blockIdx.z;
  const int jt0 = z * (SEQ/16/JSPA), jt1 = jt0 + SEQ/16/JSPA;
  const size_t bbase = (size_t)b * NH * SEQ * HD;

  // premix weights with log2(e) folded in: exp(x) == exp2(x*log2e)
  f16x4 wlA;
  f32x4 blC;
#pragma unroll
  for (int j = 0; j < 4; ++j) {
    const int k = q*4 + j;
    wlA[j] = (n16 < 12 && k < 12) ? (_Float16)(Wl[n16*12 + k] * LOG2E) : (_Float16)0.f;
    blC[j] = (k < 12) ? bl[k] * LOG2E : 0.f;
  }

  bf16x8 qf[3][2];
#pragma unroll
  for (int hh = 0; hh < 3; ++hh)
#pragma unroll
    for (int cc = 0; cc < 2; ++cc)
      qf[hh][cc] = *(const bf16x8*)(Qg + bbase + ((size_t)(h0+hh)*SEQ + i0 + n16)*HD + cc*32 + q*8);

  const f32x4 z4 = {0.f, 0.f, 0.f, 0.f};

  float lrun[4][4];
#pragma unroll
  for (int c = 0; c < 4; ++c)
#pragma unroll
    for (int r = 0; r < 4; ++r) lrun[c][r] = 0.f;

  bf16x8 kC[3][2];

#pragma unroll 2
  for (int jt = jt0; jt < jt1; ++jt) {
    const int buf = jt & 1;
    // load K(jt) — used at interval end; covered by the mix below
#pragma unroll
    for (int hh = 0; hh < 3; ++hh) {
      const __bf16* kp = Kg + bbase + ((size_t)(h0+hh)*SEQ + jt*16 + n16)*HD + q*8;
      kC[hh][0] = *(const bf16x8*)kp;
      kC[hh][1] = *(const bf16x8*)(kp + 32);
    }
    // accumulate-mix(jt-1) from Sl[1-buf]
    if (jt > jt0) {
      const int sb = 1 - buf;
#pragma unroll
      for (int c = 0; c < 4; ++c) {
        const int i = w*4 + c;
        f16x4 sf;
#pragma unroll
        for (int dd = 0; dd < 4; ++dd) {
          int h = q*4 + dd; if (h > 11) h = 11;
          sf[dd] = Sl[sb][h][i*20 + n16];
        }
        f32x4 sm = __builtin_amdgcn_mfma_f32_16x16x16f16(wlA, sf, blC, 0, 0, 0);
#pragma unroll
        for (int r = 0; r < 4; ++r) lrun[c][r] += __builtin_amdgcn_exp2f(sm[r]);
      }
    }
    // S(jt) -> Sl[buf]
#pragma unroll
    for (int hh = 0; hh < 3; ++hh) {
      f32x4 s = __builtin_amdgcn_mfma_f32_16x16x32_bf16(kC[hh][0], qf[hh][0], z4, 0, 0, 0);
      s = __builtin_amdgcn_mfma_f32_16x16x32_bf16(kC[hh][1], qf[hh][1], s, 0, 0, 0);
      f16x4 sh = { (_Float16)s[0], (_Float16)s[1], (_Float16)s[2], (_Float16)s[3] };
      *(f16x4*)&Sl[buf][h0+hh][n16*20 + q*4] = sh;
    }
    __syncthreads();
  }
  // tail: accumulate-mix(jt1-1) from Sl[1] (jt1 even)
  {
#pragma unroll
    for (int c = 0; c < 4; ++c) {
      const int i = w*4 + c;
      f16x4 sf;
#pragma unroll
      for (int dd = 0; dd < 4; ++dd) {
        int h = q*4 + dd; if (h > 11) h = 11;
        sf[dd] = Sl[1][h][i*20 + n16];
      }
      f32x4 sm = __builtin_amdgcn_mfma_f32_16x16x16f16(wlA, sf, blC, 0, 0, 0);
#pragma unroll
      for (int r = 0; r < 4; ++r) lrun[c][r] += __builtin_amdgcn_exp2f(sm[r]);
    }
  }

  // reduce over the 16 j-lanes; lane n16==0 of each q-group writes
  const int tile = b * (SEQ/16) + blockIdx.y;
#pragma unroll
  for (int c = 0; c < 4; ++c) {
#pragma unroll
    for (int r = 0; r < 4; ++r) {
      float l = lrun[c][r];
      l += __shfl_xor(l, 1);
      l += __shfl_xor(l, 2);
      l += __shfl_xor(l, 4);
      l += __shfl_xor(l, 8);
      const int g = q*4 + r;
      if (n16 == 0 && g < 12)
        lpart[(((size_t)tile*JSPA + z)*12 + g)*16 + w*4 + c] = l;
    }
  }
}

// ---------------------------------------------------------------------------
// K2b: PV pass, j-split 2 ways, grid (8, 64, 2) = 1024 = 4 blocks/CU exact.
// Lag-2 pipeline (round-4 proven): issue K(jt)+V(jt-2) -> mix(jt-1) ->
// PV(jt-2) -> S(jt) -> barrier. NO kN/vN rotation (-72 regs/wave) so
// total VGPR+AGPR fits 128 -> 4 waves/SIMD (round-5's occupancy fix).
// Writes f16 partials Ap0/Ap1 summed in gemm_proj (round-1/5 proven).
// ---------------------------------------------------------------------------
__global__ __launch_bounds__(256, 4) void attn_pv(
    const __bf16* __restrict__ Qg, const __bf16* __restrict__ Kg,
    const _Float16* __restrict__ Vt2,
    const float* __restrict__ Wl, const float* __restrict__ bl,
    const float* __restrict__ Ww, const float* __restrict__ bw,
    const float* __restrict__ lpart,
    _Float16* __restrict__ Ap0, _Float16* __restrict__ Ap1)
{
  __shared__ _Float16 Sl[2][12][324];    // f16 scores
  __shared__ _Float16 Pl[2][16 * 248];   // [buf][i*248 + g2*20 + j]

  const int t = threadIdx.x, lane = t & 63, w = t >> 6;
  const int n16 = lane & 15, q = lane >> 4;
  const int h0 = w * 3;
  const int b = blockIdx.x, i0 = blockIdx.y * 16, z = blockIdx.z;
  const int jt0 = z * (SEQ/16/JSPB), jt1 = jt0 + SEQ/16/JSPB;
  const size_t bbase = (size_t)b * NH * SEQ * HD;

  f16x4 wlA, wwA;
  f32x4 blC, bwC;
#pragma unroll
  for (int j = 0; j < 4; ++j) {
    const int k = q*4 + j;
    wlA[j] = (n16 < 12 && k < 12) ? (_Float16)(Wl[n16*12 + k] * LOG2E) : (_Float16)0.f;
    wwA[j] = (n16 < 12 && k < 12) ? (_Float16)Ww[n16*12 + k] : (_Float16)0.f;
    blC[j] = (k < 12) ? bl[k] * LOG2E : 0.f;
    bwC[j] = (k < 12) ? bw[k] : 0.f;
  }

  // combined 1/l from the JSPA partial sums
  const int tile = b * (SEQ/16) + blockIdx.y;
  float linv[4][4];
#pragma unroll
  for (int c = 0; c < 4; ++c)
#pragma unroll
    for (int r = 0; r < 4; ++r) {
      const int g = q*4 + r;
      if (g < 12) {
        float l = 0.f;
#pragma unroll
        for (int zz = 0; zz < JSPA; ++zz)
          l += lpart[(((size_t)tile*JSPA + zz)*12 + g)*16 + w*4 + c];
        linv[c][r] = 1.0f / l;
      } else {
        linv[c][r] = 0.f;
      }
    }

  bf16x8 qf[3][2];
#pragma unroll
  for (int hh = 0; hh < 3; ++hh)
#pragma unroll
    for (int cc = 0; cc < 2; ++cc)
      qf[hh][cc] = *(const bf16x8*)(Qg + bbase + ((size_t)(h0+hh)*SEQ + i0 + n16)*HD + cc*32 + q*8);

  const f32x4 z4 = {0.f, 0.f, 0.f, 0.f};

  f32x4 oacc[3][4];
#pragma unroll
  for (int hh = 0; hh < 3; ++hh)
#pragma unroll
    for (int dc = 0; dc < 4; ++dc) oacc[hh][dc] = z4;

  bf16x8 kC[3][2];
  f16x4 vC[3][4];

#pragma unroll 2
  for (int jt = jt0; jt < jt1; ++jt) {
    const int buf = jt & 1;
    // issue K(jt) — used at interval end
#pragma unroll
    for (int hh = 0; hh < 3; ++hh) {
      const __bf16* kp = Kg + bbase + ((size_t)(h0+hh)*SEQ + jt*16 + n16)*HD + q*8;
      kC[hh][0] = *(const bf16x8*)kp;
      kC[hh][1] = *(const bf16x8*)(kp + 32);
    }
    // issue V(jt-2) — used by PV below, covered by the mix
    if (jt >= jt0 + 2) {
#pragma unroll
      for (int hh = 0; hh < 3; ++hh) {
        const _Float16* vb = Vt2 + (((size_t)(b*NH + h0 + hh)*64 + (jt-2))*HD)*16;
#pragma unroll
        for (int dc = 0; dc < 4; ++dc)
          vC[hh][dc] = *(const f16x4*)(vb + (size_t)(dc*16 + n16)*16 + q*4);
      }
    }
    // mix(jt-1): Sl[1-buf] -> Pl[buf]
    if (jt > jt0) {
      const int sb = 1 - buf;
#pragma unroll
      for (int c = 0; c < 4; ++c) {
        const int i = w*4 + c;
        f16x4 sf;
#pragma unroll
        for (int dd = 0; dd < 4; ++dd) {
          int h = q*4 + dd; if (h > 11) h = 11;
          sf[dd] = Sl[sb][h][i*20 + n16];
        }
        f32x4 sm = __builtin_amdgcn_mfma_f32_16x16x16f16(wlA, sf, blC, 0, 0, 0);
        f16x4 pnf;
#pragma unroll
        for (int r = 0; r < 4; ++r)
          pnf[r] = (_Float16)(__builtin_amdgcn_exp2f(sm[r]) * linv[c][r]);
        f32x4 p2 = __builtin_amdgcn_mfma_f32_16x16x16f16(wwA, pnf, bwC, 0, 0, 0);
        if (q < 3) {
#pragma unroll
          for (int r = 0; r < 4; ++r)
            Pl[buf][i*248 + (q*4 + r)*20 + n16] = (_Float16)p2[r];
        }
      }
    }
    // PV(jt-2): Pl[1-buf] x vC
    if (jt >= jt0 + 2) {
#pragma unroll
      for (int hh = 0; hh < 3; ++hh) {
        const int g2 = h0 + hh;
        f16x4 pa = *(const f16x4*)&Pl[1 - buf][n16*248 + g2*20 + q*4];
#pragma unroll
        for (int dc = 0; dc < 4; ++dc)
          oacc[hh][dc] = __builtin_amdgcn_mfma_f32_16x16x16f16(pa, vC[hh][dc], oacc[hh][dc], 0, 0, 0);
      }
    }
    // S(jt) -> Sl[buf]
#pragma unroll
    for (int hh = 0; hh < 3; ++hh) {
      f32x4 s = __builtin_amdgcn_mfma_f32_16x16x32_bf16(kC[hh][0], qf[hh][0], z4, 0, 0, 0);
      s = __builtin_amdgcn_mfma_f32_16x16x32_bf16(kC[hh][1], qf[hh][1], s, 0, 0, 0);
      f16x4 sh = { (_Float16)s[0], (_Float16)s[1], (_Float16)s[2], (_Float16)s[3] };
      *(f16x4*)&Sl[buf][h0+hh][n16*20 + q*4] = sh;
    }
    __syncthreads();
  }

  // tail: mix(jt1-1) -> Pl[0]; PV(jt1-2) from Pl[1]; barrier; PV(jt1-1) from Pl[0]
  {
    // V(jt1-2)
#pragma unroll
    for (int hh = 0; hh < 3; ++hh) {
      const _Float16* vb = Vt2 + (((size_t)(b*NH + h0 + hh)*64 + (jt1-2))*HD)*16;
#pragma unroll
      for (int dc = 0; dc < 4; ++dc)
        vC[hh][dc] = *(const f16x4*)(vb + (size_t)(dc*16 + n16)*16 + q*4);
    }
    // mix(jt1-1) from Sl[1] -> Pl[0]   (jt1 even)
#pragma unroll
    for (int c = 0; c < 4; ++c) {
      const int i = w*4 + c;
      f16x4 sf;
#pragma unroll
      for (int dd = 0; dd < 4; ++dd) {
        int h = q*4 + dd; if (h > 11) h = 11;
        sf[dd] = Sl[1][h][i*20 + n16];
      }
      f32x4 sm = __builtin_amdgcn_mfma_f32_16x16x16f16(wlA, sf, blC, 0, 0, 0);
      f16x4 pnf;
#pragma unroll
      for (int r = 0; r < 4; ++r)
        pnf[r] = (_Float16)(__builtin_amdgcn_exp2f(sm[r]) * linv[c][r]);
      f32x4 p2 = __builtin_amdgcn_mfma_f32_16x16x16f16(wwA, pnf, bwC, 0, 0, 0);
      if (q < 3) {
#pragma unroll
        for (int r = 0; r < 4; ++r)
          Pl[0][i*248 + (q*4 + r)*20 + n16] = (_Float16)p2[r];
      }
    }
    // PV(jt1-2) from Pl[1]
#pragma unroll
    for (int hh = 0; hh < 3; ++hh) {
      const int g2 = h0 + hh;
      f16x4 pa = *(const f16x4*)&Pl[1][n16*248 + g2*20 + q*4];
#pragma unroll
      for (int dc = 0; dc < 4; ++dc)
        oacc[hh][dc] = __builtin_amdgcn_mfma_f32_16x16x16f16(pa, vC[hh][dc], oacc[hh][dc], 0, 0, 0);
    }
    // issue V(jt1-1) before the barrier (latency covered by barrier wait)
#pragma unroll
    for (int hh = 0; hh < 3; ++hh) {
      const _Float16* vb = Vt2 + (((size_t)(b*NH + h0 + hh)*64 + (jt1-1))*HD)*16;
#pragma unroll
      for (int dc = 0; dc < 4; ++dc)
        vC[hh][dc] = *(const f16x4*)(vb + (size_t)(dc*16 + n16)*16 + q*4);
    }
    __syncthreads();
    // PV(jt1-1) from Pl[0]
#pragma unroll
    for (int hh = 0; hh < 3; ++hh) {
      const int g2 = h0 + hh;
      f16x4 pa = *(const f16x4*)&Pl[0][n16*248 + g2*20 + q*4];
#pragma unroll
      for (int dc = 0; dc < 4; ++dc)
        oacc[hh][dc] = __builtin_amdgcn_mfma_f32_16x16x16f16(pa, vC[hh][dc], oacc[hh][dc], 0, 0, 0);
    }
  }

  _Float16* Ao = z ? Ap1 : Ap0;
#pragma unroll
  for (int hh = 0; hh < 3; ++hh)
#pragma unroll
    for (int dc = 0; dc < 4; ++dc)
#pragma unroll
      for (int r = 0; r < 4; ++r)
        Ao[((size_t)(b*SEQ + i0 + q*4 + r))*DIM + (h0+hh)*HD + dc*16 + n16] =
            (_Float16)oacc[hh][dc][r];
}

// ---------------------------------------------------------------------------
// K3: output projection; sums the two f16 attention partials during staging
// (packed f16 adds), f16 MFMA. Round-1/5-proven numerics.
// ---------------------------------------------------------------------------
__global__ __launch_bounds__(256) void gemm_proj(
    const _Float16* __restrict__ A0, const _Float16* __restrict__ A1,
    const _Float16* __restrict__ WpT,
    const float* __restrict__ bp, float* __restrict__ Out)
{
  __shared__ _Float16 As[128 * 40];
  __shared__ _Float16 Bs[128 * 40];

  const int t = threadIdx.x, lane = t & 63, w = t >> 6;
  const int n16 = lane & 15, q = lane >> 4;
  const int m0 = blockIdx.y * 128, n0 = blockIdx.x * 128;
  const int wm = (w >> 1) * 64, wn = (w & 1) * 64;

  const int srow = t >> 2, scol = (t & 3) * 8;
  const _Float16* Ag0 = A0 + (size_t)(m0 + srow) * DIM + scol;
  const _Float16* Ag1 = A1 + (size_t)(m0 + srow) * DIM + scol;
  const _Float16* Bg = WpT + (size_t)(n0 + srow) * DIM + scol;

  f32x4 acc[4][4];
#pragma unroll
  for (int nt = 0; nt < 4; ++nt) {
    const float bpv = bp[n0 + wn + nt*16 + n16];
#pragma unroll
    for (int mt = 0; mt < 4; ++mt)
#pragma unroll
      for (int r = 0; r < 4; ++r) acc[mt][nt][r] = bpv;
  }

  for (int kb = 0; kb < DIM; kb += 32) {
    __syncthreads();
    f16x8 a0 = *(const f16x8*)(Ag0 + kb) + *(const f16x8*)(Ag1 + kb);
    f16x8 a1 = *(const f16x8*)(Ag0 + (size_t)64 * DIM + kb) +
               *(const f16x8*)(Ag1 + (size_t)64 * DIM + kb);
    f16x8 b0 = *(const f16x8*)(Bg + kb);
    f16x8 b1 = *(const f16x8*)(Bg + (size_t)64 * DIM + kb);
    *(f16x8*)&As[srow * 40 + scol] = a0;
    *(f16x8*)&As[(srow + 64) * 40 + scol] = a1;
    *(f16x8*)&Bs[srow * 40 + scol] = b0;
    *(f16x8*)&Bs[(srow + 64) * 40 + scol] = b1;
    __syncthreads();

    f16x8 af[4], bg[4];
#pragma unroll
    for (int mt = 0; mt < 4; ++mt)
      af[mt] = *(const f16x8*)&As[(wm + mt*16 + n16) * 40 + q*8];
#pragma unroll
    for (int nt = 0; nt < 4; ++nt)
      bg[nt] = *(const f16x8*)&Bs[(wn + nt*16 + n16) * 40 + q*8];
#pragma unroll
    for (int mt = 0; mt < 4; ++mt)
#pragma unroll
      for (int nt = 0; nt < 4; ++nt)
        acc[mt][nt] = __builtin_amdgcn_mfma_f32_16x16x32_f16(af[mt], bg[nt], acc[mt][nt], 0, 0, 0);
  }

#pragma unroll
  for (int nt = 0; nt < 4; ++nt) {
    const int n = n0 + wn + nt*16 + n16;
#pragma unroll
    for (int mt = 0; mt < 4; ++mt)
#pragma unroll
      for (int r = 0; r < 4; ++r) {
        const int row = m0 + wm + mt*16 + q*4 + r;
        Out[(size_t)row * DIM + n] = acc[mt][nt][r];
      }
  }
}

extern "C" void kernel_launch(void* const* d_in, const int* in_sizes, int n_in,
                              void* d_out, int out_size, void* d_ws, size_t ws_size,
                              hipStream_t stream) {
  const float* x  = (const float*)d_in[0];
  const float* Wq = (const float*)d_in[1];
  const float* Wk = (const float*)d_in[2];
  const float* Wv = (const float*)d_in[3];
  const float* Wl = (const float*)d_in[4];
  const float* bl = (const float*)d_in[5];
  const float* Ww = (const float*)d_in[6];
  const float* bw = (const float*)d_in[7];
  const float* Wp = (const float*)d_in[8];
  const float* bp = (const float*)d_in[9];

  char* p = (char*)d_ws;
  const size_t WSZ = (size_t)DIM * DIM * 2;                 // 1,179,648 B
  const size_t TSZ = (size_t)BATCH * NH * SEQ * HD * 2;     // 12,582,912 B
  const size_t LSZ = (size_t)BATCH * (SEQ/16) * JSPA * 12 * 16 * 4;
  __bf16*   WqT = (__bf16*)p;            p += WSZ;   // WqT|WkT|WvT contiguous:
  __bf16*   WkT = (__bf16*)p;            p += WSZ;   // = the 2304x768 B matrix
  __bf16*   WvT = (__bf16*)p;            p += WSZ;
  _Float16* WpT = (_Float16*)p;          p += WSZ;
  __bf16*   Q   = (__bf16*)p;            p += TSZ;
  __bf16*   K   = (__bf16*)p;            p += TSZ;
  _Float16* V2  = (_Float16*)p;          p += TSZ;
  _Float16* Ap0 = (_Float16*)p;          p += TSZ;
  __bf16*   Xb  = (__bf16*)p;            p += TSZ;
  float*    lpart = (float*)p;           p += LSZ;
  // Xb is dead after gemm_qkv; attn_pv (later in stream order) reuses it:
  _Float16* Ap1 = (_Float16*)Xb;

  xcvt<<<dim3((BATCH*SEQ*DIM)/(256*8)), 256, 0, stream>>>(x, Xb);
  wtrans<<<dim3(24, 24, 4), 256, 0, stream>>>(Wq, Wk, Wv, Wp, WqT, WkT, WvT, WpT);
  gemm_qkv<<<dim3(18, 64), 256, 0, stream>>>(Xb, WqT, Q, K, V2);
  attn_sums<<<dim3(BATCH, SEQ/16, JSPA), 256, 0, stream>>>(Q, K, Wl, bl, lpart);
  attn_pv<<<dim3(BATCH, SEQ/16, JSPB), 256, 0, stream>>>(Q, K, V2, Wl, bl, Ww, bw,
                                                         lpart, Ap0, Ap1);
  gemm_proj<<<dim3(6, 64), 256, 0, stream>>>(Ap0, Ap1, WpT, bp, (float*)d_out);
}

// Round 7
// 435.308 us; speedup vs baseline: 2.0390x; 2.0390x over previous
//
#include <hip/hip_runtime.h>
#include <hip/hip_bf16.h>

#define DIM 768
#define NH 12
#define HD 64
#define SEQ 1024
#define BATCH 8
#define LOG2E 1.44269504f

typedef __bf16 bf16x8 __attribute__((ext_vector_type(8)));
typedef _Float16 f16x4 __attribute__((ext_vector_type(4)));
typedef float f32x4 __attribute__((ext_vector_type(4)));

// ---------------------------------------------------------------------------
// K-1: convert X fp32 -> bf16 (one-shot, ~38 MB traffic).
// ---------------------------------------------------------------------------
__global__ __launch_bounds__(256) void xcvt(
    const float* __restrict__ X, __bf16* __restrict__ Xb)
{
  const size_t i = ((size_t)blockIdx.x * 256 + threadIdx.x) * 8;
  float4 a0 = *(const float4*)(X + i);
  float4 a1 = *(const float4*)(X + i + 4);
  bf16x8 v = { (__bf16)a0.x, (__bf16)a0.y, (__bf16)a0.z, (__bf16)a0.w,
               (__bf16)a1.x, (__bf16)a1.y, (__bf16)a1.z, (__bf16)a1.w };
  *(bf16x8*)(Xb + i) = v;
}

// ---------------------------------------------------------------------------
// K0: transpose + cvt 768x768 fp32 W -> bf16 WT[n][k]. blockIdx.z selects.
// ---------------------------------------------------------------------------
__global__ __launch_bounds__(256) void wtrans(
    const float* __restrict__ Wq, const float* __restrict__ Wk,
    const float* __restrict__ Wv, const float* __restrict__ Wp,
    __bf16* __restrict__ Tq, __bf16* __restrict__ Tk,
    __bf16* __restrict__ Tv, __bf16* __restrict__ Tp)
{
  const int z = blockIdx.z;
  const float* W = (z==0) ? Wq : (z==1) ? Wk : (z==2) ? Wv : Wp;
  __bf16* T = (z==0) ? Tq : (z==1) ? Tk : (z==2) ? Tv : Tp;
  __shared__ float tile[32][33];
  const int t = threadIdx.x, tx = t & 31, ty = t >> 5;
  const int k0 = blockIdx.y * 32, n0 = blockIdx.x * 32;
#pragma unroll
  for (int u = 0; u < 4; ++u)
    tile[ty + u*8][tx] = W[(size_t)(k0 + ty + u*8) * DIM + n0 + tx];
  __syncthreads();
#pragma unroll
  for (int u = 0; u < 4; ++u)
    T[(size_t)(n0 + ty + u*8) * DIM + k0 + tx] = (__bf16)tile[tx][ty + u*8];
}

// ---------------------------------------------------------------------------
// K1: fused QKV projection, LDS-staged MFMA GEMM (proven).
// ---------------------------------------------------------------------------
__global__ __launch_bounds__(256) void gemm_qkv(
    const __bf16* __restrict__ Xb, const __bf16* __restrict__ WT,
    __bf16* __restrict__ Qo, __bf16* __restrict__ Ko, _Float16* __restrict__ Vt2)
{
  __shared__ __bf16 As[128 * 40];
  __shared__ __bf16 Bs[128 * 40];

  const int t = threadIdx.x, lane = t & 63, w = t >> 6;
  const int n16 = lane & 15, q = lane >> 4;
  const int m0 = blockIdx.y * 128, n0 = blockIdx.x * 128;
  const int wm = (w >> 1) * 64, wn = (w & 1) * 64;

  const int srow = t >> 2, scol = (t & 3) * 8;
  const __bf16* Ag = Xb + (size_t)(m0 + srow) * DIM + scol;
  const __bf16* Bg = WT + (size_t)(n0 + srow) * DIM + scol;

  f32x4 acc[4][4];
#pragma unroll
  for (int mt = 0; mt < 4; ++mt)
#pragma unroll
    for (int nt = 0; nt < 4; ++nt) acc[mt][nt] = (f32x4){0.f,0.f,0.f,0.f};

  for (int kb = 0; kb < DIM; kb += 32) {
    __syncthreads();
    bf16x8 a0 = *(const bf16x8*)(Ag + kb);
    bf16x8 a1 = *(const bf16x8*)(Ag + (size_t)64 * DIM + kb);
    bf16x8 b0 = *(const bf16x8*)(Bg + kb);
    bf16x8 b1 = *(const bf16x8*)(Bg + (size_t)64 * DIM + kb);
    *(bf16x8*)&As[srow * 40 + scol] = a0;
    *(bf16x8*)&As[(srow + 64) * 40 + scol] = a1;
    *(bf16x8*)&Bs[srow * 40 + scol] = b0;
    *(bf16x8*)&Bs[(srow + 64) * 40 + scol] = b1;
    __syncthreads();

    bf16x8 af[4], bg[4];
#pragma unroll
    for (int mt = 0; mt < 4; ++mt)
      af[mt] = *(const bf16x8*)&As[(wm + mt*16 + n16) * 40 + q*8];
#pragma unroll
    for (int nt = 0; nt < 4; ++nt)
      bg[nt] = *(const bf16x8*)&Bs[(wn + nt*16 + n16) * 40 + q*8];
#pragma unroll
    for (int mt = 0; mt < 4; ++mt)
#pragma unroll
      for (int nt = 0; nt < 4; ++nt)
        acc[mt][nt] = __builtin_amdgcn_mfma_f32_16x16x32_bf16(af[mt], bg[nt], acc[mt][nt], 0, 0, 0);
  }

#pragma unroll
  for (int nt = 0; nt < 4; ++nt) {
    const int n = n0 + wn + nt*16 + n16;
    const int z = n / DIM, c = n % DIM;
    const int h = c >> 6, d = c & 63;
#pragma unroll
    for (int mt = 0; mt < 4; ++mt) {
#pragma unroll
      for (int r = 0; r < 4; ++r) {
        const int row = m0 + wm + mt*16 + q*4 + r;
        const int bb = row >> 10, ii = row & 1023;
        const float v = acc[mt][nt][r];
        if (z == 0)
          Qo[(((size_t)bb*NH + h)*SEQ + ii)*HD + d] = (__bf16)(v * 0.125f);
        else if (z == 1)
          Ko[(((size_t)bb*NH + h)*SEQ + ii)*HD + d] = (__bf16)v;
        else
          Vt2[((((size_t)bb*NH + h)*64 + (ii >> 4))*HD + d)*16 + (ii & 15)] = (_Float16)v;
      }
    }
  }
}

// ---------------------------------------------------------------------------
// K2: fused talking-heads attention — round-0 proven structure (lag-1 K/V
// register prefetch, one barrier per 16-key interval), with two proven
// upgrades: (1) grid (BATCH, SEQ/16) so flattened wg%8 = batch -> per-XCD
// L2 holds one batch's K/V/Q (round-4: FETCH 154->18.5 MB); (2) f16 Sl +
// exp2-folded premix (round-3 pv proven: LDS 47->31.4 KB, conflicts down).
// ---------------------------------------------------------------------------
__global__ __launch_bounds__(256, 2) void attn_fused(
    const __bf16* __restrict__ Qg, const __bf16* __restrict__ Kg,
    const _Float16* __restrict__ Vt2,
    const float* __restrict__ Wl, const float* __restrict__ bl,
    const float* __restrict__ Ww, const float* __restrict__ bw,
    __bf16* __restrict__ Aout)
{
  __shared__ _Float16 Sl[2][12][324];    // f16 scores
  __shared__ _Float16 Pl[2][16 * 248];   // [buf][i*248 + g2*20 + j]

  const int t = threadIdx.x, lane = t & 63, w = t >> 6;
  const int n16 = lane & 15, q = lane >> 4;
  const int h0 = w * 3;
  const int b = blockIdx.x, i0 = blockIdx.y * 16;
  const size_t bbase = (size_t)b * NH * SEQ * HD;

  // premix weights with log2(e) folded in: exp(x) == exp2(x*log2e)
  f16x4 wlA, wwA;
  f32x4 blC, bwC;
#pragma unroll
  for (int j = 0; j < 4; ++j) {
    const int k = q*4 + j;
    wlA[j] = (n16 < 12 && k < 12) ? (_Float16)(Wl[n16*12 + k] * LOG2E) : (_Float16)0.f;
    wwA[j] = (n16 < 12 && k < 12) ? (_Float16)Ww[n16*12 + k] : (_Float16)0.f;
    blC[j] = (k < 12) ? bl[k] * LOG2E : 0.f;
    bwC[j] = (k < 12) ? bw[k] : 0.f;
  }

  bf16x8 qf[3][2];
#pragma unroll
  for (int hh = 0; hh < 3; ++hh)
#pragma unroll
    for (int cc = 0; cc < 2; ++cc)
      qf[hh][cc] = *(const bf16x8*)(Qg + bbase + ((size_t)(h0+hh)*SEQ + i0 + n16)*HD + cc*32 + q*8);

  const f32x4 z4 = {0.f, 0.f, 0.f, 0.f};

  // ---------------- Phase A: l[g][i], K prefetched one jt ahead ----------
  float lrun[4][4];
#pragma unroll
  for (int c = 0; c < 4; ++c)
#pragma unroll
    for (int r = 0; r < 4; ++r) lrun[c][r] = 0.f;

  bf16x8 kC[3][2], kN[3][2];
#pragma unroll
  for (int hh = 0; hh < 3; ++hh) {
    const __bf16* kp = Kg + bbase + ((size_t)(h0+hh)*SEQ + n16)*HD + q*8;
    kC[hh][0] = *(const bf16x8*)kp;
    kC[hh][1] = *(const bf16x8*)(kp + 32);
  }

#pragma unroll 2
  for (int jt = 0; jt < SEQ/16; ++jt) {
    const int buf = jt & 1;
    const int jn = (jt < SEQ/16 - 1) ? jt + 1 : jt;
#pragma unroll
    for (int hh = 0; hh < 3; ++hh) {
      const __bf16* kp = Kg + bbase + ((size_t)(h0+hh)*SEQ + jn*16 + n16)*HD + q*8;
      kN[hh][0] = *(const bf16x8*)kp;
      kN[hh][1] = *(const bf16x8*)(kp + 32);
    }
#pragma unroll
    for (int hh = 0; hh < 3; ++hh) {
      f32x4 s = __builtin_amdgcn_mfma_f32_16x16x32_bf16(kC[hh][0], qf[hh][0], z4, 0, 0, 0);
      s = __builtin_amdgcn_mfma_f32_16x16x32_bf16(kC[hh][1], qf[hh][1], s, 0, 0, 0);
      f16x4 sh = { (_Float16)s[0], (_Float16)s[1], (_Float16)s[2], (_Float16)s[3] };
      *(f16x4*)&Sl[buf][h0+hh][n16*20 + q*4] = sh;
    }
    __syncthreads();
#pragma unroll
    for (int c = 0; c < 4; ++c) {
      const int i = w*4 + c;
      f16x4 sf;
#pragma unroll
      for (int dd = 0; dd < 4; ++dd) {
        int h = q*4 + dd; if (h > 11) h = 11;
        sf[dd] = Sl[buf][h][i*20 + n16];
      }
      f32x4 sm = __builtin_amdgcn_mfma_f32_16x16x16f16(wlA, sf, blC, 0, 0, 0);
#pragma unroll
      for (int r = 0; r < 4; ++r) lrun[c][r] += __builtin_amdgcn_exp2f(sm[r]);
    }
#pragma unroll
    for (int hh = 0; hh < 3; ++hh) { kC[hh][0] = kN[hh][0]; kC[hh][1] = kN[hh][1]; }
  }

  float linv[4][4];
#pragma unroll
  for (int c = 0; c < 4; ++c)
#pragma unroll
    for (int r = 0; r < 4; ++r) {
      float l = lrun[c][r];
      l += __shfl_xor(l, 1);
      l += __shfl_xor(l, 2);
      l += __shfl_xor(l, 4);
      l += __shfl_xor(l, 8);
      linv[c][r] = 1.0f / l;
    }

  // ---------------- Phase B: 1 barrier/jt, PV lagged by one ----------------
  f32x4 oacc[3][4];
#pragma unroll
  for (int hh = 0; hh < 3; ++hh)
#pragma unroll
    for (int dc = 0; dc < 4; ++dc) oacc[hh][dc] = z4;

  f16x4 vC[3][4], vN[3][4];
#pragma unroll
  for (int hh = 0; hh < 3; ++hh) {
    const __bf16* kp = Kg + bbase + ((size_t)(h0+hh)*SEQ + n16)*HD + q*8;
    kC[hh][0] = *(const bf16x8*)kp;
    kC[hh][1] = *(const bf16x8*)(kp + 32);
  }

#pragma unroll 2
  for (int jt = 0; jt < SEQ/16; ++jt) {
    const int buf = jt & 1;
    const int jn = (jt < SEQ/16 - 1) ? jt + 1 : jt;
    // prefetch K(jt+1)
#pragma unroll
    for (int hh = 0; hh < 3; ++hh) {
      const __bf16* kp = Kg + bbase + ((size_t)(h0+hh)*SEQ + jn*16 + n16)*HD + q*8;
      kN[hh][0] = *(const bf16x8*)kp;
      kN[hh][1] = *(const bf16x8*)(kp + 32);
    }
    // prefetch V(jt) (consumed by PV next interval)
#pragma unroll
    for (int hh = 0; hh < 3; ++hh) {
      const _Float16* vb = Vt2 + (((size_t)(b*NH + h0 + hh)*64 + jt)*HD)*16;
#pragma unroll
      for (int dc = 0; dc < 4; ++dc)
        vN[hh][dc] = *(const f16x4*)(vb + (size_t)(dc*16 + n16)*16 + q*4);
    }
    // S(jt)
#pragma unroll
    for (int hh = 0; hh < 3; ++hh) {
      f32x4 s = __builtin_amdgcn_mfma_f32_16x16x32_bf16(kC[hh][0], qf[hh][0], z4, 0, 0, 0);
      s = __builtin_amdgcn_mfma_f32_16x16x32_bf16(kC[hh][1], qf[hh][1], s, 0, 0, 0);
      f16x4 sh = { (_Float16)s[0], (_Float16)s[1], (_Float16)s[2], (_Float16)s[3] };
      *(f16x4*)&Sl[buf][h0+hh][n16*20 + q*4] = sh;
    }
    __syncthreads();
    // premix -> exp2 -> normalize -> postmix -> Pl[buf]
#pragma unroll
    for (int c = 0; c < 4; ++c) {
      const int i = w*4 + c;
      f16x4 sf;
#pragma unroll
      for (int dd = 0; dd < 4; ++dd) {
        int h = q*4 + dd; if (h > 11) h = 11;
        sf[dd] = Sl[buf][h][i*20 + n16];
      }
      f32x4 sm = __builtin_amdgcn_mfma_f32_16x16x16f16(wlA, sf, blC, 0, 0, 0);
      f16x4 pnf;
#pragma unroll
      for (int r = 0; r < 4; ++r)
        pnf[r] = (_Float16)(__builtin_amdgcn_exp2f(sm[r]) * linv[c][r]);
      f32x4 p2 = __builtin_amdgcn_mfma_f32_16x16x16f16(wwA, pnf, bwC, 0, 0, 0);
      if (q < 3) {
#pragma unroll
        for (int r = 0; r < 4; ++r)
          Pl[buf][i*248 + (q*4 + r)*20 + n16] = (_Float16)p2[r];
      }
    }
    // PV(jt-1) from the other buffer, V frags prefetched last interval
    if (jt > 0) {
#pragma unroll
      for (int hh = 0; hh < 3; ++hh) {
        const int g2 = h0 + hh;
        f16x4 pa = *(const f16x4*)&Pl[1 - buf][n16*248 + g2*20 + q*4];
#pragma unroll
        for (int dc = 0; dc < 4; ++dc)
          oacc[hh][dc] = __builtin_amdgcn_mfma_f32_16x16x16f16(pa, vC[hh][dc], oacc[hh][dc], 0, 0, 0);
      }
    }
    // rotate prefetch buffers
#pragma unroll
    for (int hh = 0; hh < 3; ++hh) {
      kC[hh][0] = kN[hh][0]; kC[hh][1] = kN[hh][1];
#pragma unroll
      for (int dc = 0; dc < 4; ++dc) vC[hh][dc] = vN[hh][dc];
    }
  }
  __syncthreads();
  // tail: PV(63) from Pl[1], vC = V(63)
#pragma unroll
  for (int hh = 0; hh < 3; ++hh) {
    const int g2 = h0 + hh;
    f16x4 pa = *(const f16x4*)&Pl[1][n16*248 + g2*20 + q*4];
#pragma unroll
    for (int dc = 0; dc < 4; ++dc)
      oacc[hh][dc] = __builtin_amdgcn_mfma_f32_16x16x16f16(pa, vC[hh][dc], oacc[hh][dc], 0, 0, 0);
  }

#pragma unroll
  for (int hh = 0; hh < 3; ++hh)
#pragma unroll
    for (int dc = 0; dc < 4; ++dc)
#pragma unroll
      for (int r = 0; r < 4; ++r)
        Aout[((size_t)(b*SEQ + i0 + q*4 + r))*DIM + (h0+hh)*HD + dc*16 + n16] =
            (__bf16)oacc[hh][dc][r];
}

// ---------------------------------------------------------------------------
// K3: output projection, LDS-staged MFMA GEMM (proven).
// ---------------------------------------------------------------------------
__global__ __launch_bounds__(256) void gemm_proj(
    const __bf16* __restrict__ A, const __bf16* __restrict__ WpT,
    const float* __restrict__ bp, float* __restrict__ Out)
{
  __shared__ __bf16 As[128 * 40];
  __shared__ __bf16 Bs[128 * 40];

  const int t = threadIdx.x, lane = t & 63, w = t >> 6;
  const int n16 = lane & 15, q = lane >> 4;
  const int m0 = blockIdx.y * 128, n0 = blockIdx.x * 128;
  const int wm = (w >> 1) * 64, wn = (w & 1) * 64;

  const int srow = t >> 2, scol = (t & 3) * 8;
  const __bf16* Ag = A + (size_t)(m0 + srow) * DIM + scol;
  const __bf16* Bg = WpT + (size_t)(n0 + srow) * DIM + scol;

  f32x4 acc[4][4];
#pragma unroll
  for (int nt = 0; nt < 4; ++nt) {
    const float bpv = bp[n0 + wn + nt*16 + n16];
#pragma unroll
    for (int mt = 0; mt < 4; ++mt)
#pragma unroll
      for (int r = 0; r < 4; ++r) acc[mt][nt][r] = bpv;
  }

  for (int kb = 0; kb < DIM; kb += 32) {
    __syncthreads();
    bf16x8 a0 = *(const bf16x8*)(Ag + kb);
    bf16x8 a1 = *(const bf16x8*)(Ag + (size_t)64 * DIM + kb);
    bf16x8 b0 = *(const bf16x8*)(Bg + kb);
    bf16x8 b1 = *(const bf16x8*)(Bg + (size_t)64 * DIM + kb);
    *(bf16x8*)&As[srow * 40 + scol] = a0;
    *(bf16x8*)&As[(srow + 64) * 40 + scol] = a1;
    *(bf16x8*)&Bs[srow * 40 + scol] = b0;
    *(bf16x8*)&Bs[(srow + 64) * 40 + scol] = b1;
    __syncthreads();

    bf16x8 af[4], bg[4];
#pragma unroll
    for (int mt = 0; mt < 4; ++mt)
      af[mt] = *(const bf16x8*)&As[(wm + mt*16 + n16) * 40 + q*8];
#pragma unroll
    for (int nt = 0; nt < 4; ++nt)
      bg[nt] = *(const bf16x8*)&Bs[(wn + nt*16 + n16) * 40 + q*8];
#pragma unroll
    for (int mt = 0; mt < 4; ++mt)
#pragma unroll
      for (int nt = 0; nt < 4; ++nt)
        acc[mt][nt] = __builtin_amdgcn_mfma_f32_16x16x32_bf16(af[mt], bg[nt], acc[mt][nt], 0, 0, 0);
  }

#pragma unroll
  for (int nt = 0; nt < 4; ++nt) {
    const int n = n0 + wn + nt*16 + n16;
#pragma unroll
    for (int mt = 0; mt < 4; ++mt)
#pragma unroll
      for (int r = 0; r < 4; ++r) {
        const int row = m0 + wm + mt*16 + q*4 + r;
        Out[(size_t)row * DIM + n] = acc[mt][nt][r];
      }
  }
}

extern "C" void kernel_launch(void* const* d_in, const int* in_sizes, int n_in,
                              void* d_out, int out_size, void* d_ws, size_t ws_size,
                              hipStream_t stream) {
  const float* x  = (const float*)d_in[0];
  const float* Wq = (const float*)d_in[1];
  const float* Wk = (const float*)d_in[2];
  const float* Wv = (const float*)d_in[3];
  const float* Wl = (const float*)d_in[4];
  const float* bl = (const float*)d_in[5];
  const float* Ww = (const float*)d_in[6];
  const float* bw = (const float*)d_in[7];
  const float* Wp = (const float*)d_in[8];
  const float* bp = (const float*)d_in[9];

  char* p = (char*)d_ws;
  const size_t WSZ = (size_t)DIM * DIM * 2;                 // 1,179,648 B
  const size_t TSZ = (size_t)BATCH * NH * SEQ * HD * 2;     // 12,582,912 B
  __bf16*   WqT = (__bf16*)p;            p += WSZ;   // WqT|WkT|WvT contiguous:
  __bf16*   WkT = (__bf16*)p;            p += WSZ;   // = the 2304x768 B matrix
  __bf16*   WvT = (__bf16*)p;            p += WSZ;
  __bf16*   WpT = (__bf16*)p;            p += WSZ;
  __bf16*   Q   = (__bf16*)p;            p += TSZ;
  __bf16*   K   = (__bf16*)p;            p += TSZ;
  _Float16* V2  = (_Float16*)p;          p += TSZ;
  __bf16*   AO  = (__bf16*)p;            p += TSZ;
  __bf16*   Xb  = (__bf16*)p;            p += TSZ;

  xcvt<<<dim3((BATCH*SEQ*DIM)/(256*8)), 256, 0, stream>>>(x, Xb);
  wtrans<<<dim3(24, 24, 4), 256, 0, stream>>>(Wq, Wk, Wv, Wp, WqT, WkT, WvT, WpT);
  gemm_qkv<<<dim3(18, 64), 256, 0, stream>>>(Xb, WqT, Q, K, V2);
  attn_fused<<<dim3(BATCH, SEQ/16), 256, 0, stream>>>(Q, K, V2, Wl, bl, Ww, bw, AO);
  gemm_proj<<<dim3(6, 64), 256, 0, stream>>>(AO, WpT, bp, (float*)d_out);
}

// Round 8
// 422.879 us; speedup vs baseline: 2.0990x; 1.0294x over previous
//
#include <hip/hip_runtime.h>
#include <hip/hip_bf16.h>

#define DIM 768
#define NH 12
#define HD 64
#define SEQ 1024
#define BATCH 8
#define LOG2E 1.44269504f

typedef __bf16 bf16x8 __attribute__((ext_vector_type(8)));
typedef _Float16 f16x4 __attribute__((ext_vector_type(4)));
typedef float f32x4 __attribute__((ext_vector_type(4)));

// async global->LDS copy, 16 B per lane; LDS dest must be wave-uniform base
// (+ lane*16 implicit). Source is per-lane.
__device__ __forceinline__ void gload_lds16(const __bf16* g, __bf16* l) {
  __builtin_amdgcn_global_load_lds(
      (const __attribute__((address_space(1))) void*)g,
      (__attribute__((address_space(3))) void*)l, 16, 0, 0);
}

// ---------------------------------------------------------------------------
// K-1: convert X fp32 -> bf16 (one-shot, ~38 MB traffic).
// ---------------------------------------------------------------------------
__global__ __launch_bounds__(256) void xcvt(
    const float* __restrict__ X, __bf16* __restrict__ Xb)
{
  const size_t i = ((size_t)blockIdx.x * 256 + threadIdx.x) * 8;
  float4 a0 = *(const float4*)(X + i);
  float4 a1 = *(const float4*)(X + i + 4);
  bf16x8 v = { (__bf16)a0.x, (__bf16)a0.y, (__bf16)a0.z, (__bf16)a0.w,
               (__bf16)a1.x, (__bf16)a1.y, (__bf16)a1.z, (__bf16)a1.w };
  *(bf16x8*)(Xb + i) = v;
}

// ---------------------------------------------------------------------------
// K0: transpose + cvt 768x768 fp32 W -> bf16 WT[n][k]. blockIdx.z selects.
// ---------------------------------------------------------------------------
__global__ __launch_bounds__(256) void wtrans(
    const float* __restrict__ Wq, const float* __restrict__ Wk,
    const float* __restrict__ Wv, const float* __restrict__ Wp,
    __bf16* __restrict__ Tq, __bf16* __restrict__ Tk,
    __bf16* __restrict__ Tv, __bf16* __restrict__ Tp)
{
  const int z = blockIdx.z;
  const float* W = (z==0) ? Wq : (z==1) ? Wk : (z==2) ? Wv : Wp;
  __bf16* T = (z==0) ? Tq : (z==1) ? Tk : (z==2) ? Tv : Tp;
  __shared__ float tile[32][33];
  const int t = threadIdx.x, tx = t & 31, ty = t >> 5;
  const int k0 = blockIdx.y * 32, n0 = blockIdx.x * 32;
#pragma unroll
  for (int u = 0; u < 4; ++u)
    tile[ty + u*8][tx] = W[(size_t)(k0 + ty + u*8) * DIM + n0 + tx];
  __syncthreads();
#pragma unroll
  for (int u = 0; u < 4; ++u)
    T[(size_t)(n0 + ty + u*8) * DIM + k0 + tx] = (__bf16)tile[tx][ty + u*8];
}

// ---------------------------------------------------------------------------
// K1: fused QKV projection. m97-style staging: global_load_lds width=16 into
// unpadded [128][32] LDS (lane-linear dest: thread t -> byte t*16). Read-side
// 8-way conflict on ds_read_b128 is the known m97 trade (guide: 874 TF).
// ---------------------------------------------------------------------------
__global__ __launch_bounds__(256) void gemm_qkv(
    const __bf16* __restrict__ Xb, const __bf16* __restrict__ WT,
    __bf16* __restrict__ Qo, __bf16* __restrict__ Ko, _Float16* __restrict__ Vt2)
{
  __shared__ __bf16 As[128 * 32];
  __shared__ __bf16 Bs[128 * 32];

  const int t = threadIdx.x, lane = t & 63, w = t >> 6;
  const int n16 = lane & 15, q = lane >> 4;
  const int m0 = blockIdx.y * 128, n0 = blockIdx.x * 128;
  const int wm = (w >> 1) * 64, wn = (w & 1) * 64;

  const int srow = t >> 2, scol = (t & 3) * 8;
  const __bf16* Ag = Xb + (size_t)(m0 + srow) * DIM + scol;
  const __bf16* Bg = WT + (size_t)(n0 + srow) * DIM + scol;
  // wave-uniform LDS bases: wave w covers bytes [w*1024, w*1024+1024)
  __bf16* AsW0 = &As[w * 512];
  __bf16* AsW1 = &As[2048 + w * 512];
  __bf16* BsW0 = &Bs[w * 512];
  __bf16* BsW1 = &Bs[2048 + w * 512];

  f32x4 acc[4][4];
#pragma unroll
  for (int mt = 0; mt < 4; ++mt)
#pragma unroll
    for (int nt = 0; nt < 4; ++nt) acc[mt][nt] = (f32x4){0.f,0.f,0.f,0.f};

  for (int kb = 0; kb < DIM; kb += 32) {
    __syncthreads();
    gload_lds16(Ag + kb, AsW0);
    gload_lds16(Ag + (size_t)64 * DIM + kb, AsW1);
    gload_lds16(Bg + kb, BsW0);
    gload_lds16(Bg + (size_t)64 * DIM + kb, BsW1);
    __syncthreads();

    bf16x8 af[4], bg[4];
#pragma unroll
    for (int mt = 0; mt < 4; ++mt)
      af[mt] = *(const bf16x8*)&As[(wm + mt*16 + n16) * 32 + q*8];
#pragma unroll
    for (int nt = 0; nt < 4; ++nt)
      bg[nt] = *(const bf16x8*)&Bs[(wn + nt*16 + n16) * 32 + q*8];
#pragma unroll
    for (int mt = 0; mt < 4; ++mt)
#pragma unroll
      for (int nt = 0; nt < 4; ++nt)
        acc[mt][nt] = __builtin_amdgcn_mfma_f32_16x16x32_bf16(af[mt], bg[nt], acc[mt][nt], 0, 0, 0);
  }

#pragma unroll
  for (int nt = 0; nt < 4; ++nt) {
    const int n = n0 + wn + nt*16 + n16;
    const int z = n / DIM, c = n % DIM;
    const int h = c >> 6, d = c & 63;
#pragma unroll
    for (int mt = 0; mt < 4; ++mt) {
#pragma unroll
      for (int r = 0; r < 4; ++r) {
        const int row = m0 + wm + mt*16 + q*4 + r;
        const int bb = row >> 10, ii = row & 1023;
        const float v = acc[mt][nt][r];
        if (z == 0)
          Qo[(((size_t)bb*NH + h)*SEQ + ii)*HD + d] = (__bf16)(v * 0.125f);
        else if (z == 1)
          Ko[(((size_t)bb*NH + h)*SEQ + ii)*HD + d] = (__bf16)v;
        else
          Vt2[((((size_t)bb*NH + h)*64 + (ii >> 4))*HD + d)*16 + (ii & 15)] = (_Float16)v;
      }
    }
  }
}

// ---------------------------------------------------------------------------
// K2: fused talking-heads attention — round-7 proven (256 us), plus:
// (a) s_setprio(1) around S-MFMA and PV-MFMA clusters (T5: +4-7% attn);
// (b) PV issued immediately after the barrier, before the premix chain,
//     so its ds_read_b64 latency overlaps the premix LDS reads.
// ---------------------------------------------------------------------------
__global__ __launch_bounds__(256, 2) void attn_fused(
    const __bf16* __restrict__ Qg, const __bf16* __restrict__ Kg,
    const _Float16* __restrict__ Vt2,
    const float* __restrict__ Wl, const float* __restrict__ bl,
    const float* __restrict__ Ww, const float* __restrict__ bw,
    __bf16* __restrict__ Aout)
{
  __shared__ _Float16 Sl[2][12][324];    // f16 scores
  __shared__ _Float16 Pl[2][16 * 248];   // [buf][i*248 + g2*20 + j]

  const int t = threadIdx.x, lane = t & 63, w = t >> 6;
  const int n16 = lane & 15, q = lane >> 4;
  const int h0 = w * 3;
  const int b = blockIdx.x, i0 = blockIdx.y * 16;
  const size_t bbase = (size_t)b * NH * SEQ * HD;

  // premix weights with log2(e) folded in: exp(x) == exp2(x*log2e)
  f16x4 wlA, wwA;
  f32x4 blC, bwC;
#pragma unroll
  for (int j = 0; j < 4; ++j) {
    const int k = q*4 + j;
    wlA[j] = (n16 < 12 && k < 12) ? (_Float16)(Wl[n16*12 + k] * LOG2E) : (_Float16)0.f;
    wwA[j] = (n16 < 12 && k < 12) ? (_Float16)Ww[n16*12 + k] : (_Float16)0.f;
    blC[j] = (k < 12) ? bl[k] * LOG2E : 0.f;
    bwC[j] = (k < 12) ? bw[k] : 0.f;
  }

  bf16x8 qf[3][2];
#pragma unroll
  for (int hh = 0; hh < 3; ++hh)
#pragma unroll
    for (int cc = 0; cc < 2; ++cc)
      qf[hh][cc] = *(const bf16x8*)(Qg + bbase + ((size_t)(h0+hh)*SEQ + i0 + n16)*HD + cc*32 + q*8);

  const f32x4 z4 = {0.f, 0.f, 0.f, 0.f};

  // ---------------- Phase A: l[g][i], K prefetched one jt ahead ----------
  float lrun[4][4];
#pragma unroll
  for (int c = 0; c < 4; ++c)
#pragma unroll
    for (int r = 0; r < 4; ++r) lrun[c][r] = 0.f;

  bf16x8 kC[3][2], kN[3][2];
#pragma unroll
  for (int hh = 0; hh < 3; ++hh) {
    const __bf16* kp = Kg + bbase + ((size_t)(h0+hh)*SEQ + n16)*HD + q*8;
    kC[hh][0] = *(const bf16x8*)kp;
    kC[hh][1] = *(const bf16x8*)(kp + 32);
  }

#pragma unroll 2
  for (int jt = 0; jt < SEQ/16; ++jt) {
    const int buf = jt & 1;
    const int jn = (jt < SEQ/16 - 1) ? jt + 1 : jt;
#pragma unroll
    for (int hh = 0; hh < 3; ++hh) {
      const __bf16* kp = Kg + bbase + ((size_t)(h0+hh)*SEQ + jn*16 + n16)*HD + q*8;
      kN[hh][0] = *(const bf16x8*)kp;
      kN[hh][1] = *(const bf16x8*)(kp + 32);
    }
    __builtin_amdgcn_s_setprio(1);
#pragma unroll
    for (int hh = 0; hh < 3; ++hh) {
      f32x4 s = __builtin_amdgcn_mfma_f32_16x16x32_bf16(kC[hh][0], qf[hh][0], z4, 0, 0, 0);
      s = __builtin_amdgcn_mfma_f32_16x16x32_bf16(kC[hh][1], qf[hh][1], s, 0, 0, 0);
      f16x4 sh = { (_Float16)s[0], (_Float16)s[1], (_Float16)s[2], (_Float16)s[3] };
      *(f16x4*)&Sl[buf][h0+hh][n16*20 + q*4] = sh;
    }
    __builtin_amdgcn_s_setprio(0);
    __syncthreads();
#pragma unroll
    for (int c = 0; c < 4; ++c) {
      const int i = w*4 + c;
      f16x4 sf;
#pragma unroll
      for (int dd = 0; dd < 4; ++dd) {
        int h = q*4 + dd; if (h > 11) h = 11;
        sf[dd] = Sl[buf][h][i*20 + n16];
      }
      f32x4 sm = __builtin_amdgcn_mfma_f32_16x16x16f16(wlA, sf, blC, 0, 0, 0);
#pragma unroll
      for (int r = 0; r < 4; ++r) lrun[c][r] += __builtin_amdgcn_exp2f(sm[r]);
    }
#pragma unroll
    for (int hh = 0; hh < 3; ++hh) { kC[hh][0] = kN[hh][0]; kC[hh][1] = kN[hh][1]; }
  }

  float linv[4][4];
#pragma unroll
  for (int c = 0; c < 4; ++c)
#pragma unroll
    for (int r = 0; r < 4; ++r) {
      float l = lrun[c][r];
      l += __shfl_xor(l, 1);
      l += __shfl_xor(l, 2);
      l += __shfl_xor(l, 4);
      l += __shfl_xor(l, 8);
      linv[c][r] = 1.0f / l;
    }

  // ---------------- Phase B: 1 barrier/jt, PV lagged by one ----------------
  f32x4 oacc[3][4];
#pragma unroll
  for (int hh = 0; hh < 3; ++hh)
#pragma unroll
    for (int dc = 0; dc < 4; ++dc) oacc[hh][dc] = z4;

  f16x4 vC[3][4], vN[3][4];
#pragma unroll
  for (int hh = 0; hh < 3; ++hh) {
    const __bf16* kp = Kg + bbase + ((size_t)(h0+hh)*SEQ + n16)*HD + q*8;
    kC[hh][0] = *(const bf16x8*)kp;
    kC[hh][1] = *(const bf16x8*)(kp + 32);
  }

#pragma unroll 2
  for (int jt = 0; jt < SEQ/16; ++jt) {
    const int buf = jt & 1;
    const int jn = (jt < SEQ/16 - 1) ? jt + 1 : jt;
    // prefetch K(jt+1)
#pragma unroll
    for (int hh = 0; hh < 3; ++hh) {
      const __bf16* kp = Kg + bbase + ((size_t)(h0+hh)*SEQ + jn*16 + n16)*HD + q*8;
      kN[hh][0] = *(const bf16x8*)kp;
      kN[hh][1] = *(const bf16x8*)(kp + 32);
    }
    // prefetch V(jt) (consumed by PV next interval)
#pragma unroll
    for (int hh = 0; hh < 3; ++hh) {
      const _Float16* vb = Vt2 + (((size_t)(b*NH + h0 + hh)*64 + jt)*HD)*16;
#pragma unroll
      for (int dc = 0; dc < 4; ++dc)
        vN[hh][dc] = *(const f16x4*)(vb + (size_t)(dc*16 + n16)*16 + q*4);
    }
    // S(jt)
    __builtin_amdgcn_s_setprio(1);
#pragma unroll
    for (int hh = 0; hh < 3; ++hh) {
      f32x4 s = __builtin_amdgcn_mfma_f32_16x16x32_bf16(kC[hh][0], qf[hh][0], z4, 0, 0, 0);
      s = __builtin_amdgcn_mfma_f32_16x16x32_bf16(kC[hh][1], qf[hh][1], s, 0, 0, 0);
      f16x4 sh = { (_Float16)s[0], (_Float16)s[1], (_Float16)s[2], (_Float16)s[3] };
      *(f16x4*)&Sl[buf][h0+hh][n16*20 + q*4] = sh;
    }
    __builtin_amdgcn_s_setprio(0);
    __syncthreads();
    // PV(jt-1) first: its LDS reads overlap the premix chain below
    if (jt > 0) {
      f16x4 pa[3];
#pragma unroll
      for (int hh = 0; hh < 3; ++hh)
        pa[hh] = *(const f16x4*)&Pl[1 - buf][n16*248 + (h0+hh)*20 + q*4];
      __builtin_amdgcn_s_setprio(1);
#pragma unroll
      for (int hh = 0; hh < 3; ++hh)
#pragma unroll
        for (int dc = 0; dc < 4; ++dc)
          oacc[hh][dc] = __builtin_amdgcn_mfma_f32_16x16x16f16(pa[hh], vC[hh][dc], oacc[hh][dc], 0, 0, 0);
      __builtin_amdgcn_s_setprio(0);
    }
    // premix -> exp2 -> normalize -> postmix -> Pl[buf]
#pragma unroll
    for (int c = 0; c < 4; ++c) {
      const int i = w*4 + c;
      f16x4 sf;
#pragma unroll
      for (int dd = 0; dd < 4; ++dd) {
        int h = q*4 + dd; if (h > 11) h = 11;
        sf[dd] = Sl[buf][h][i*20 + n16];
      }
      f32x4 sm = __builtin_amdgcn_mfma_f32_16x16x16f16(wlA, sf, blC, 0, 0, 0);
      f16x4 pnf;
#pragma unroll
      for (int r = 0; r < 4; ++r)
        pnf[r] = (_Float16)(__builtin_amdgcn_exp2f(sm[r]) * linv[c][r]);
      f32x4 p2 = __builtin_amdgcn_mfma_f32_16x16x16f16(wwA, pnf, bwC, 0, 0, 0);
      if (q < 3) {
#pragma unroll
        for (int r = 0; r < 4; ++r)
          Pl[buf][i*248 + (q*4 + r)*20 + n16] = (_Float16)p2[r];
      }
    }
    // rotate prefetch buffers
#pragma unroll
    for (int hh = 0; hh < 3; ++hh) {
      kC[hh][0] = kN[hh][0]; kC[hh][1] = kN[hh][1];
#pragma unroll
      for (int dc = 0; dc < 4; ++dc) vC[hh][dc] = vN[hh][dc];
    }
  }
  __syncthreads();
  // tail: PV(63) from Pl[1], vC = V(63)
#pragma unroll
  for (int hh = 0; hh < 3; ++hh) {
    const int g2 = h0 + hh;
    f16x4 pa = *(const f16x4*)&Pl[1][n16*248 + g2*20 + q*4];
#pragma unroll
    for (int dc = 0; dc < 4; ++dc)
      oacc[hh][dc] = __builtin_amdgcn_mfma_f32_16x16x16f16(pa, vC[hh][dc], oacc[hh][dc], 0, 0, 0);
  }

#pragma unroll
  for (int hh = 0; hh < 3; ++hh)
#pragma unroll
    for (int dc = 0; dc < 4; ++dc)
#pragma unroll
      for (int r = 0; r < 4; ++r)
        Aout[((size_t)(b*SEQ + i0 + q*4 + r))*DIM + (h0+hh)*HD + dc*16 + n16] =
            (__bf16)oacc[hh][dc][r];
}

// ---------------------------------------------------------------------------
// K3: output projection — same global_load_lds staging upgrade as K1.
// ---------------------------------------------------------------------------
__global__ __launch_bounds__(256) void gemm_proj(
    const __bf16* __restrict__ A, const __bf16* __restrict__ WpT,
    const float* __restrict__ bp, float* __restrict__ Out)
{
  __shared__ __bf16 As[128 * 32];
  __shared__ __bf16 Bs[128 * 32];

  const int t = threadIdx.x, lane = t & 63, w = t >> 6;
  const int n16 = lane & 15, q = lane >> 4;
  const int m0 = blockIdx.y * 128, n0 = blockIdx.x * 128;
  const int wm = (w >> 1) * 64, wn = (w & 1) * 64;

  const int srow = t >> 2, scol = (t & 3) * 8;
  const __bf16* Ag = A + (size_t)(m0 + srow) * DIM + scol;
  const __bf16* Bg = WpT + (size_t)(n0 + srow) * DIM + scol;
  __bf16* AsW0 = &As[w * 512];
  __bf16* AsW1 = &As[2048 + w * 512];
  __bf16* BsW0 = &Bs[w * 512];
  __bf16* BsW1 = &Bs[2048 + w * 512];

  f32x4 acc[4][4];
#pragma unroll
  for (int nt = 0; nt < 4; ++nt) {
    const float bpv = bp[n0 + wn + nt*16 + n16];
#pragma unroll
    for (int mt = 0; mt < 4; ++mt)
#pragma unroll
      for (int r = 0; r < 4; ++r) acc[mt][nt][r] = bpv;
  }

  for (int kb = 0; kb < DIM; kb += 32) {
    __syncthreads();
    gload_lds16(Ag + kb, AsW0);
    gload_lds16(Ag + (size_t)64 * DIM + kb, AsW1);
    gload_lds16(Bg + kb, BsW0);
    gload_lds16(Bg + (size_t)64 * DIM + kb, BsW1);
    __syncthreads();

    bf16x8 af[4], bg[4];
#pragma unroll
    for (int mt = 0; mt < 4; ++mt)
      af[mt] = *(const bf16x8*)&As[(wm + mt*16 + n16) * 32 + q*8];
#pragma unroll
    for (int nt = 0; nt < 4; ++nt)
      bg[nt] = *(const bf16x8*)&Bs[(wn + nt*16 + n16) * 32 + q*8];
#pragma unroll
    for (int mt = 0; mt < 4; ++mt)
#pragma unroll
      for (int nt = 0; nt < 4; ++nt)
        acc[mt][nt] = __builtin_amdgcn_mfma_f32_16x16x32_bf16(af[mt], bg[nt], acc[mt][nt], 0, 0, 0);
  }

#pragma unroll
  for (int nt = 0; nt < 4; ++nt) {
    const int n = n0 + wn + nt*16 + n16;
#pragma unroll
    for (int mt = 0; mt < 4; ++mt)
#pragma unroll
      for (int r = 0; r < 4; ++r) {
        const int row = m0 + wm + mt*16 + q*4 + r;
        Out[(size_t)row * DIM + n] = acc[mt][nt][r];
      }
  }
}

extern "C" void kernel_launch(void* const* d_in, const int* in_sizes, int n_in,
                              void* d_out, int out_size, void* d_ws, size_t ws_size,
                              hipStream_t stream) {
  const float* x  = (const float*)d_in[0];
  const float* Wq = (const float*)d_in[1];
  const float* Wk = (const float*)d_in[2];
  const float* Wv = (const float*)d_in[3];
  const float* Wl = (const float*)d_in[4];
  const float* bl = (const float*)d_in[5];
  const float* Ww = (const float*)d_in[6];
  const float* bw = (const float*)d_in[7];
  const float* Wp = (const float*)d_in[8];
  const float* bp = (const float*)d_in[9];

  char* p = (char*)d_ws;
  const size_t WSZ = (size_t)DIM * DIM * 2;                 // 1,179,648 B
  const size_t TSZ = (size_t)BATCH * NH * SEQ * HD * 2;     // 12,582,912 B
  __bf16*   WqT = (__bf16*)p;            p += WSZ;   // WqT|WkT|WvT contiguous:
  __bf16*   WkT = (__bf16*)p;            p += WSZ;   // = the 2304x768 B matrix
  __bf16*   WvT = (__bf16*)p;            p += WSZ;
  __bf16*   WpT = (__bf16*)p;            p += WSZ;
  __bf16*   Q   = (__bf16*)p;            p += TSZ;
  __bf16*   K   = (__bf16*)p;            p += TSZ;
  _Float16* V2  = (_Float16*)p;          p += TSZ;
  __bf16*   AO  = (__bf16*)p;            p += TSZ;
  __bf16*   Xb  = (__bf16*)p;            p += TSZ;

  xcvt<<<dim3((BATCH*SEQ*DIM)/(256*8)), 256, 0, stream>>>(x, Xb);
  wtrans<<<dim3(24, 24, 4), 256, 0, stream>>>(Wq, Wk, Wv, Wp, WqT, WkT, WvT, WpT);
  gemm_qkv<<<dim3(18, 64), 256, 0, stream>>>(Xb, WqT, Q, K, V2);
  attn_fused<<<dim3(BATCH, SEQ/16), 256, 0, stream>>>(Q, K, V2, Wl, bl, Ww, bw, AO);
  gemm_proj<<<dim3(6, 64), 256, 0, stream>>>(AO, WpT, bp, (float*)d_out);
}